// Round 9
// baseline (125.905 us; speedup 1.0000x reference)
//
#include <hip/hip_runtime.h>

// DecoupledSOLOHead: SOLO mask decode + Matrix NMS (gaussian), MI355X/gfx950.
//
// R9 vs R8 (passed, 125.3 us; top-5 all harness 256MiB ws-poison fills ~41us +
// ~20us input restore = fixed floor; our 4 kernels + gaps ~60us):
//  - d2col [500x500] (99% zeros; 1MB zero-fill + 1MB decay scan) replaced by
//    compact per-j (idx, iou^2) lists: m_j = min(min_i comp2[i],
//    min_k comp2[idx_k] - d2_k) since label-mismatch terms reduce to comp2[i].
//  - part_sumT deleted: transpose reduces S (float) and C (popcount) per det
//    from the LDS tile it already holds (8 thr/det, shfl width=8, one
//    atomicAdd per det per block = 7.7k total atomics).
//  - pair_iou: score section + per-pair ci popcount/second shfl chain deleted;
//    counts from cnt_acc staged in LDS. Final rescoring folded into decay.
//  - scores now have ~1e-5 float-atomic-order jitter (threshold 5.1e-3).

#define N_DET 500
#define HW    (200 * 304)        // 60800
#define TILE  64
#define NT    (HW / TILE)        // 950 tiles, exact
#define PSTR  512                // det stride in tile-major arrays
#define DSTR  950                // tile stride in det-major arrays
#define NW2   (NT / 2)           // 475 ulonglong2 granules
#define CAP   512                // per-j pair-list capacity (>= any class size)
#define MASK_THR 0.005f
#define SIGMA 2.0f

// ---------------- Kernel A: pixel-tiled broadcast decode + bit-pack ------------
__global__ __launch_bounds__(512) void maskgen_kernel(
    const float* __restrict__ seg_x, const float* __restrict__ seg_y,
    const int* __restrict__ x_inds, const int* __restrict__ y_inds,
    unsigned long long* __restrict__ packed_t,  // [NT][PSTR] tile-major
    float* __restrict__ part_sum)               // [NT][PSTR]
{
    __shared__ __align__(16) float sx[128 * 64];     // 32,768 B
    __shared__ __align__(16) float sy[128 * 64];     // 32,768 B
    const int t   = blockIdx.x;
    const int tid = threadIdx.x;
    const int base = t * TILE;

    for (int e = tid; e < 128 * 16; e += 512) {
        const int r  = e >> 4;
        const int c4 = (e & 15) << 2;
        *(float4*)(sx + (r << 6) + c4) = *(const float4*)(seg_x + (size_t)r * HW + base + c4);
        *(float4*)(sy + (r << 6) + c4) = *(const float4*)(seg_y + (size_t)r * HW + base + c4);
    }
    __syncthreads();

    // thread = det; lane-rotated phase f=(k+tid)&15 -> conflict-free b128 reads
    if (tid < N_DET) {
        const float4* __restrict__ rx4 = (const float4*)(sx + (x_inds[tid] << 6));
        const float4* __restrict__ ry4 = (const float4*)(sy + (y_inds[tid] << 6));
        float ssum = 0.0f;
        unsigned long long w = 0ull;
        #pragma unroll
        for (int k = 0; k < 16; ++k) {
            const int f = (k + tid) & 15;
            const float4 xv = rx4[f];
            const float4 yv = ry4[f];
            const float p0 = xv.x * yv.x, p1 = xv.y * yv.y,
                        p2 = xv.z * yv.z, p3 = xv.w * yv.w;
            const int b0 = p0 > MASK_THR, b1 = p1 > MASK_THR,
                      b2 = p2 > MASK_THR, b3 = p3 > MASK_THR;
            ssum += (b0 ? p0 : 0.0f) + (b1 ? p1 : 0.0f)
                  + (b2 ? p2 : 0.0f) + (b3 ? p3 : 0.0f);
            const unsigned int nib = (unsigned)(b0 | (b1 << 1) | (b2 << 2) | (b3 << 3));
            w |= (unsigned long long)nib << (f << 2);
        }
        packed_t[(size_t)t * PSTR + tid] = w;          // coalesced
        part_sum[(size_t)t * PSTR + tid] = ssum;       // coalesced
    }
}

// ------- Kernel T: 64x64 transpose -> det-major bits, + per-det stats ----------
__global__ __launch_bounds__(512) void transpose_kernel(
    const unsigned long long* __restrict__ packed_t,  // [NT][PSTR]
    const float* __restrict__ part_sum,               // [NT][PSTR]
    unsigned long long* __restrict__ packed_d,        // [N_DET][DSTR]
    float* __restrict__ ssum_acc,                     // [N_DET] pre-zeroed
    int*   __restrict__ cnt_acc)                      // [N_DET] pre-zeroed
{
    __shared__ unsigned long long tp[64 * 65];        // 33,280 B
    __shared__ float              ts[64 * 65];        // 16,640 B
    const int t0  = blockIdx.x * 64;                  // 15 x-tiles -> 960 (>=950)
    const int d0  = blockIdx.y * 64;                  // 8 y-tiles  -> 512
    const int tid = threadIdx.x;
    const int lane = tid & 63, wav = tid >> 6;        // 8 waves

    #pragma unroll
    for (int k = 0; k < 8; ++k) {
        const int r  = (k << 3) + wav;
        const int gt = t0 + r;
        unsigned long long v = 0ull; float s = 0.0f;
        if (gt < NT) {
            v = packed_t[(size_t)gt * PSTR + d0 + lane];   // coalesced
            s = part_sum[(size_t)gt * PSTR + d0 + lane];
        }
        tp[r * 65 + lane] = v;
        ts[r * 65 + lane] = s;
    }
    __syncthreads();

    // transposed write-out (det-major bits)
    const int gt = t0 + lane;
    #pragma unroll
    for (int k = 0; k < 8; ++k) {
        const int m = (k << 3) + wav;
        const int d = d0 + m;
        if (gt < NT && d < N_DET)
            packed_d[(size_t)d * DSTR + gt] = tp[lane * 65 + m];  // coalesced
    }

    // per-det stats over this 64-tile strip: 8 threads per det
    const int dl = tid >> 3;                          // det-local 0..63
    const int q  = tid & 7;
    float S = 0.0f; int C = 0;
    #pragma unroll
    for (int k = 0; k < 8; ++k) {
        const int r = (k << 3) + q;
        S += ts[r * 65 + dl];
        C += __popcll(tp[r * 65 + dl]);
    }
    #pragma unroll
    for (int d = 4; d; d >>= 1) {
        S += __shfl_down(S, d, 8);
        C += __shfl_down(C, d, 8);
    }
    const int dg = d0 + dl;
    if (q == 0 && dg < N_DET) {
        atomicAdd(ssum_acc + dg, S);
        atomicAdd(cnt_acc + dg, C);
    }
}

// ------- Kernel B: same-class IoU via popcount -> compact pair lists -----------
__global__ __launch_bounds__(256) void pair_iou_kernel(
    const unsigned long long* __restrict__ packed_d,   // [N_DET][DSTR]
    const int* __restrict__ labels,
    const int* __restrict__ cnt_acc,
    float* __restrict__ comp2,    // [N] comp_iou^2
    float* __restrict__ pd2,      // [N][CAP] iou^2 per same-class pair
    int*   __restrict__ pidx,     // [N][CAP] partner index i
    int*   __restrict__ pcnt)     // [N] list length
{
    const int j   = blockIdx.x;
    const int tid = threadIdx.x;
    const int lane = tid & 63, wav = tid >> 6;

    __shared__ int   s_lab[N_DET];
    __shared__ float s_cf[N_DET];
    __shared__ int   s_list[N_DET];
    __shared__ int   s_cnt;
    __shared__ float s_max[4];

    if (tid == 0) s_cnt = 0;
    for (int i = tid; i < N_DET; i += 256) {
        s_lab[i] = labels[i];
        s_cf[i]  = (float)cnt_acc[i];
    }
    __syncthreads();

    const int   lj = s_lab[j];
    const float cj = s_cf[j];
    for (int i = tid; i < j; i += 256)
        if (s_lab[i] == lj) { const int p = atomicAdd(&s_cnt, 1); s_list[p] = i; }
    __syncthreads();
    const int cnt = s_cnt;

    // preload j's bit-row, coalesced ull2 (8 granules per lane)
    const ulonglong2* __restrict__ pj2 = (const ulonglong2*)(packed_d + (size_t)j * DSTR);
    ulonglong2 bj[8];
    #pragma unroll
    for (int q = 0; q < 8; ++q) {
        const int w = lane + (q << 6);
        if (w < NW2) bj[q] = pj2[w];
        else { bj[q].x = 0ull; bj[q].y = 0ull; }
    }

    float wmax = 0.0f;
    for (int p = wav; p < cnt; p += 4) {       // one wave per pair
        const int i = s_list[p];
        const ulonglong2* __restrict__ pi2 = (const ulonglong2*)(packed_d + (size_t)i * DSTR);
        int inter = 0;
        #pragma unroll
        for (int q = 0; q < 8; ++q) {
            const int w = lane + (q << 6);
            if (w < NW2) {
                const ulonglong2 a = pi2[w];   // coalesced 1 KB/instr
                inter += __popcll(a.x & bj[q].x) + __popcll(a.y & bj[q].y);
            }
        }
        #pragma unroll
        for (int off = 32; off; off >>= 1) inter += __shfl_down(inter, off);
        if (lane == 0) {
            const float uni = s_cf[i] + cj - (float)inter;
            const float iou = (float)inter / fmaxf(uni, 1e-6f);
            pd2 [(size_t)j * CAP + p] = iou * iou;     // dense slots 0..cnt-1
            pidx[(size_t)j * CAP + p] = i;
            wmax = fmaxf(wmax, iou);
        }
    }
    if (lane == 0) s_max[wav] = wmax;
    __syncthreads();
    if (tid == 0) {
        const float c = fmaxf(fmaxf(s_max[0], s_max[1]), fmaxf(s_max[2], s_max[3]));
        comp2[j] = c * c;
        pcnt[j]  = cnt;
    }
}

// ---------------- Kernel C: decay coef + rescore + final output ----------------
__global__ __launch_bounds__(64) void decay_kernel(
    const float* __restrict__ comp2,
    const float* __restrict__ pd2,
    const int*   __restrict__ pidx,
    const int*   __restrict__ pcnt,
    const float* __restrict__ ssum_acc,
    const int*   __restrict__ cnt_acc,
    const float* __restrict__ cate_scores,
    float* __restrict__ out)
{
    const int j = blockIdx.x;
    const int lane = threadIdx.x;
    // label-mismatch / diagonal terms reduce to comp2[i]; pairs add -d2 correction
    float m = 1e30f;
    for (int i = lane; i < N_DET; i += 64) m = fminf(m, comp2[i]);
    const int c = pcnt[j];
    for (int k = lane; k < c; k += 64)
        m = fminf(m, comp2[pidx[(size_t)j * CAP + k]] - pd2[(size_t)j * CAP + k]);
    #pragma unroll
    for (int off = 32; off; off >>= 1)
        m = fminf(m, __shfl_down(m, off));
    if (lane == 0) {
        const float C = (float)cnt_acc[j];
        const float score = cate_scores[j] * (ssum_acc[j] / fmaxf(C, 1.0f));
        out[j] = score * expf(SIGMA * m);
    }
}

extern "C" void kernel_launch(void* const* d_in, const int* in_sizes, int n_in,
                              void* d_out, int out_size, void* d_ws, size_t ws_size,
                              hipStream_t stream) {
    const float* cate_scores = (const float*)d_in[0];
    const float* seg_x       = (const float*)d_in[1];
    const float* seg_y       = (const float*)d_in[2];
    const int*   labels      = (const int*)d_in[3];
    const int*   x_inds      = (const int*)d_in[4];
    const int*   y_inds      = (const int*)d_in[5];
    float* out = (float*)d_out;

    // workspace layout (16B-aligned); total ~11.7 MB
    char* ws = (char*)d_ws;
    unsigned long long* packed_t = (unsigned long long*)(ws + 0);        // 950*512*8 = 3,891,200
    unsigned long long* packed_d = (unsigned long long*)(ws + 3891200);  // 500*950*8 = 3,800,000
    float* pd2      = (float*)(ws + 7691200);                            // 500*512*4 = 1,024,000
    int*   pidx     = (int*)  (ws + 8715200);                            // 1,024,000
    int*   pcnt     = (int*)  (ws + 9739200);                            // 2,000
    float* comp2    = (float*)(ws + 9741200);                            // 2,000
    float* ssum_acc = (float*)(ws + 9743200);                            // 2,000
    int*   cnt_acc  = (int*)  (ws + 9745200);                            // 2,000
    float* part_sum = (float*)(ws + 9747200);                            // 950*512*4 = 1,945,600

    hipMemsetAsync(ws + 9743200, 0, 4000, stream);    // ssum_acc + cnt_acc
    maskgen_kernel  <<<NT, 512, 0, stream>>>(seg_x, seg_y, x_inds, y_inds,
                                             packed_t, part_sum);
    transpose_kernel<<<dim3(15, 8), 512, 0, stream>>>(packed_t, part_sum,
                                                      packed_d, ssum_acc, cnt_acc);
    pair_iou_kernel <<<N_DET, 256, 0, stream>>>(packed_d, labels, cnt_acc,
                                                comp2, pd2, pidx, pcnt);
    decay_kernel    <<<N_DET, 64, 0, stream>>>(comp2, pd2, pidx, pcnt,
                                               ssum_acc, cnt_acc, cate_scores, out);
}